// Round 4
// baseline (235.003 us; speedup 1.0000x reference)
//
#include <hip/hip_runtime.h>
#include <math.h>

// Problem constants
#define B_   2
#define F_   4
#define HW_  4096
#define C_   64
#define L_   16384       // F*HW
#define NROWS 32768      // B*F*HW = B*L
#define DI_  96
#define DS_  16
#define DR_  4
#define DC_  4
#define MH_  96
#define CL_  32          // scan chunk length
#define NC_  512         // chunks per batch (L/CL)
#define NCT_ 1024        // total chunks (B*NC)
#define NPAIR 1536       // DI*DS

// ---------------- K0: prep: mod1/mod2 = cdp @ kernels, Aneg = -exp(A_log),
// Wcat[96][128] = [ B-cols(16) | C-cols(16) | x_proj_w[:,:4] @ dt_proj_w (96) ]
__global__ void k0_prep(const float* __restrict__ cdp,
                        const float* __restrict__ vd1,
                        const float* __restrict__ vd2,
                        const float* __restrict__ A_log,
                        const float* __restrict__ x_proj_w,
                        const float* __restrict__ dt_proj_w,
                        float* __restrict__ mod1, float* __restrict__ mod2,
                        float* __restrict__ Aneg, float* __restrict__ Wcat) {
    int t = threadIdx.x;
    for (int i = t; i < 256; i += 256) {
        int b = i >> 7, j = i & 127;
        float s1 = 0.f, s2 = 0.f;
        for (int k = 0; k < 128; ++k) {
            float c = cdp[b * 128 + k];
            s1 = fmaf(c, vd1[k * 128 + j], s1);
            s2 = fmaf(c, vd2[k * 128 + j], s2);
        }
        mod1[i] = s1; mod2[i] = s2;
    }
    for (int i = t; i < DI_ * DS_; i += 256) Aneg[i] = -__expf(A_log[i]);
    // Wcat
    for (int i = t; i < 96 * 128; i += 256) {
        int d = i >> 7, c = i & 127;
        float v;
        if (c < 16)      v = x_proj_w[d * 36 + 4 + c];
        else if (c < 32) v = x_proj_w[d * 36 + 20 + (c - 16)];
        else {
            int m = c - 32;
            v = 0.f;
            #pragma unroll
            for (int r = 0; r < 4; ++r)
                v = fmaf(x_proj_w[d * 36 + r], dt_proj_w[r * 96 + m], v);
        }
        Wcat[i] = v;
    }
}

// ---------------- K1: vdim1 (LN + mod) fused with in_proj GEMM (64 -> 192)
__global__ __launch_bounds__(256) void k1_vdim1_inproj(
    const float* __restrict__ x, const float* __restrict__ mod1,
    const float* __restrict__ ln_w, const float* __restrict__ ln_b,
    const float* __restrict__ in_proj_w,
    float* __restrict__ xsr, float* __restrict__ zsb) {
    __shared__ float tileX[32][66];
    int t = threadIdx.x;
    int row0 = blockIdx.x * 32;
    int wave = t >> 6, lane = t & 63;
    int b = row0 >> 14;
    const float* m1 = mod1 + b * 128;

    for (int rr = 0; rr < 8; ++rr) {
        int rloc = wave * 8 + rr;
        float v = x[(row0 + rloc) * 64 + lane];
        float s = v, s2 = v * v;
        #pragma unroll
        for (int off = 32; off; off >>= 1) { s += __shfl_xor(s, off); s2 += __shfl_xor(s2, off); }
        float mean = s * (1.0f / 64.0f);
        float var = s2 * (1.0f / 64.0f) - mean * mean;
        float inv = rsqrtf(var + 1e-6f);
        float xn = (v - mean) * inv * ln_w[lane] + ln_b[lane];
        tileX[rloc][lane] = xn * m1[lane] + m1[64 + lane];
    }
    __syncthreads();

    int tr = t >> 4;          // 16 row-groups of 2
    int tc = t & 15;          // 16 col-groups of 12
    float acc[2][12];
    #pragma unroll
    for (int i = 0; i < 2; ++i)
        #pragma unroll
        for (int j = 0; j < 12; ++j) acc[i][j] = 0.f;
    for (int c = 0; c < 64; ++c) {
        float x0 = tileX[tr * 2][c];
        float x1 = tileX[tr * 2 + 1][c];
        const float* wp = &in_proj_w[c * 192 + tc * 12];
        float4 wa = *(const float4*)wp;
        float4 wb = *(const float4*)(wp + 4);
        float4 wc = *(const float4*)(wp + 8);
        float w[12] = {wa.x, wa.y, wa.z, wa.w, wb.x, wb.y, wb.z, wb.w, wc.x, wc.y, wc.z, wc.w};
        #pragma unroll
        for (int j = 0; j < 12; ++j) {
            acc[0][j] = fmaf(x0, w[j], acc[0][j]);
            acc[1][j] = fmaf(x1, w[j], acc[1][j]);
        }
    }
    #pragma unroll
    for (int i = 0; i < 2; ++i) {
        int row = row0 + tr * 2 + i;
        if (tc < 8) {
            #pragma unroll
            for (int j = 0; j < 12; ++j)
                xsr[row * 96 + tc * 12 + j] = acc[i][j];
        } else {
            #pragma unroll
            for (int j = 0; j < 12; ++j) {
                float v = acc[i][j];
                zsb[row * 96 + (tc - 8) * 12 + j] = v / (1.0f + __expf(-v));
            }
        }
    }
}

// ---------------- K2: conv(k=4)+silu then fused GEMM xst(96) @ Wcat(128)
// cols: 0..15 -> Bm, 16..31 -> Cm, 32..127 -> softplus(+dt_b) -> dtb
__global__ __launch_bounds__(256) void k2_conv_gemm(
    const float* __restrict__ xsr,
    const float* __restrict__ conv_w, const float* __restrict__ conv_b,
    const float* __restrict__ Wcat, const float* __restrict__ dt_proj_b,
    float* __restrict__ xsc, float* __restrict__ dtb,
    float* __restrict__ Bm, float* __restrict__ Cm) {
    __shared__ float xst[32][97];
    int t = threadIdx.x;
    int row0 = blockIdx.x * 32;
    int bbase = row0 & ~16383;

    // conv + silu straight from global (rows L2/L1-cached across blocks)
    for (int idx = t; idx < 32 * 96; idx += 256) {
        int l = idx / 96, d = idx % 96;
        int grow = row0 + l;
        float a = conv_b[d];
        #pragma unroll
        for (int k = 0; k < 4; ++k) {
            int gr = grow - 3 + k;
            float xv = (gr >= bbase) ? xsr[gr * 96 + d] : 0.f;
            a = fmaf(xv, conv_w[d * 4 + k], a);
        }
        float sv = a / (1.0f + __expf(-a));
        xst[l][d] = sv;
        xsc[grow * 96 + d] = sv;
    }
    __syncthreads();

    // GEMM 32x96x128: 2 rows x 8 cols per thread
    int tr = t >> 4, tc = t & 15;
    float acc[2][8];
    #pragma unroll
    for (int i = 0; i < 2; ++i)
        #pragma unroll
        for (int j = 0; j < 8; ++j) acc[i][j] = 0.f;
    for (int d = 0; d < 96; ++d) {
        float x0 = xst[tr * 2][d];
        float x1 = xst[tr * 2 + 1][d];
        const float* wp = &Wcat[d * 128 + tc * 8];
        float4 wa = *(const float4*)wp;
        float4 wb = *(const float4*)(wp + 4);
        float w[8] = {wa.x, wa.y, wa.z, wa.w, wb.x, wb.y, wb.z, wb.w};
        #pragma unroll
        for (int j = 0; j < 8; ++j) {
            acc[0][j] = fmaf(x0, w[j], acc[0][j]);
            acc[1][j] = fmaf(x1, w[j], acc[1][j]);
        }
    }
    int c0 = tc * 8;
    #pragma unroll
    for (int i = 0; i < 2; ++i) {
        int row = row0 + tr * 2 + i;
        if (tc < 2) {
            *(float4*)&Bm[row * 16 + c0]     = make_float4(acc[i][0], acc[i][1], acc[i][2], acc[i][3]);
            *(float4*)&Bm[row * 16 + c0 + 4] = make_float4(acc[i][4], acc[i][5], acc[i][6], acc[i][7]);
        } else if (tc < 4) {
            int cc = c0 - 16;
            *(float4*)&Cm[row * 16 + cc]     = make_float4(acc[i][0], acc[i][1], acc[i][2], acc[i][3]);
            *(float4*)&Cm[row * 16 + cc + 4] = make_float4(acc[i][4], acc[i][5], acc[i][6], acc[i][7]);
        } else {
            int m = c0 - 32;
            float o[8];
            #pragma unroll
            for (int j = 0; j < 8; ++j) {
                float a = acc[i][j] + dt_proj_b[m + j];
                o[j] = fmaxf(a, 0.f) + log1pf(__expf(-fabsf(a)));
            }
            *(float4*)&dtb[row * 96 + m]     = make_float4(o[0], o[1], o[2], o[3]);
            *(float4*)&dtb[row * 96 + m + 4] = make_float4(o[4], o[5], o[6], o[7]);
        }
    }
}

// ---------------- scan pass 1: per-chunk aggregates. thread = (d, s-quad), 4 states in regs
__global__ __launch_bounds__(384) void s1_agg(
    const float* __restrict__ dtb, const float* __restrict__ xsc,
    const float* __restrict__ Bm, const float* __restrict__ Aneg,
    float2* __restrict__ agg) {
    int t = threadIdx.x;
    int d = t >> 2, sq = t & 3;
    int bc = blockIdx.x;                    // 0..NCT-1
    int b = bc >> 9, chunk = bc & 511;
    int row0 = b * L_ + chunk * CL_;
    float4 ac = *(const float4*)&Aneg[d * 16 + sq * 4];
    float a0 = 1.f, a1 = 1.f, a2 = 1.f, a3 = 1.f;
    float b0 = 0.f, b1 = 0.f, b2 = 0.f, b3 = 0.f;
    #pragma unroll 4
    for (int i = 0; i < CL_; ++i) {
        int row = row0 + i;
        float dtv = dtb[row * 96 + d];
        float xv  = xsc[row * 96 + d];
        float4 bv = *(const float4*)&Bm[row * 16 + sq * 4];
        float dx = dtv * xv;
        float e0 = __expf(dtv * ac.x), e1 = __expf(dtv * ac.y);
        float e2 = __expf(dtv * ac.z), e3 = __expf(dtv * ac.w);
        b0 = fmaf(b0, e0, dx * bv.x); a0 *= e0;
        b1 = fmaf(b1, e1, dx * bv.y); a1 *= e1;
        b2 = fmaf(b2, e2, dx * bv.z); a2 *= e2;
        b3 = fmaf(b3, e3, dx * bv.w); a3 *= e3;
    }
    size_t base = (size_t)bc * NPAIR + d * 16 + sq * 4;
    *(float4*)&agg[base]     = make_float4(a0, b0, a1, b1);
    *(float4*)&agg[base + 2] = make_float4(a2, b2, a3, b3);
}

// ---------------- scan pass 2: Hillis-Steele scan across 512 chunks, block per (b,pair)
__global__ __launch_bounds__(512) void s2_scan(const float2* __restrict__ agg,
                                               float* __restrict__ initb) {
    __shared__ float sA[512], sB[512];
    int seq = blockIdx.x;                   // 0..3071
    int b = seq / NPAIR, pair = seq % NPAIR;
    int c = threadIdx.x;                    // chunk
    float2 v = agg[((size_t)(b * NC_ + c)) * NPAIR + pair];
    sA[c] = v.x; sB[c] = v.y;
    #pragma unroll
    for (int off = 1; off < 512; off <<= 1) {
        __syncthreads();
        float ap = 0.f, bp = 0.f;
        bool has = c >= off;
        if (has) { ap = sA[c - off]; bp = sB[c - off]; }
        __syncthreads();
        if (has) { sB[c] = fmaf(bp, sA[c], sB[c]); sA[c] *= ap; }
    }
    __syncthreads();
    float init = (c == 0) ? 0.f : sB[c - 1];
    initb[((size_t)(b * NC_ + c)) * NPAIR + pair] = init;
}

// ---------------- scan pass 3: replay + y = sum_s h*C + D*xs, gate silu(z)
__global__ __launch_bounds__(384) void s3_replay(
    const float* __restrict__ dtb, const float* __restrict__ xsc,
    const float* __restrict__ Bm, const float* __restrict__ Cm,
    const float* __restrict__ Aneg, const float* __restrict__ initb,
    const float* __restrict__ Dp, const float* __restrict__ zsb,
    float* __restrict__ yb) {
    int t = threadIdx.x;
    int d = t >> 2, sq = t & 3;
    int bc = blockIdx.x;
    int b = bc >> 9, chunk = bc & 511;
    int row0 = b * L_ + chunk * CL_;
    float4 ac = *(const float4*)&Aneg[d * 16 + sq * 4];
    float dcoef = Dp[d];
    float4 hv = *(const float4*)&initb[(size_t)bc * NPAIR + d * 16 + sq * 4];
    float h0 = hv.x, h1 = hv.y, h2 = hv.z, h3 = hv.w;
    #pragma unroll 2
    for (int i = 0; i < CL_; ++i) {
        int row = row0 + i;
        float dtv = dtb[row * 96 + d];
        float xv  = xsc[row * 96 + d];
        float4 bv = *(const float4*)&Bm[row * 16 + sq * 4];
        float4 cv = *(const float4*)&Cm[row * 16 + sq * 4];
        float dx = dtv * xv;
        float e0 = __expf(dtv * ac.x), e1 = __expf(dtv * ac.y);
        float e2 = __expf(dtv * ac.z), e3 = __expf(dtv * ac.w);
        h0 = fmaf(h0, e0, dx * bv.x);
        h1 = fmaf(h1, e1, dx * bv.y);
        h2 = fmaf(h2, e2, dx * bv.z);
        h3 = fmaf(h3, e3, dx * bv.w);
        float part = h0 * cv.x;
        part = fmaf(h1, cv.y, part);
        part = fmaf(h2, cv.z, part);
        part = fmaf(h3, cv.w, part);
        part += __shfl_xor(part, 1);
        part += __shfl_xor(part, 2);
        if (sq == 0) {
            float yv = part + dcoef * xv;
            yb[row * 96 + d] = yv * zsb[row * 96 + d];
        }
    }
}

// ---------------- K6: out_proj (96->64) + skip1 -> h1. 32 rows/block, 2x4 per thread.
__global__ __launch_bounds__(256) void k6_outproj(
    const float* __restrict__ yb, const float* __restrict__ opw,
    const float* __restrict__ x, const float* __restrict__ ss1,
    float* __restrict__ h1) {
    __shared__ float yt[32][100];
    int t = threadIdx.x;
    int row0 = blockIdx.x * 32;
    for (int i = t; i < 32 * 96; i += 256) {
        int l = i / 96, d = i % 96;
        yt[l][d] = yb[(row0 + l) * 96 + d];
    }
    __syncthreads();
    int tr = t >> 4, tc = t & 15;
    float acc[2][4];
    #pragma unroll
    for (int i = 0; i < 2; ++i)
        #pragma unroll
        for (int j = 0; j < 4; ++j) acc[i][j] = 0.f;
    for (int m = 0; m < 96; ++m) {
        float4 wv = *(const float4*)&opw[m * 64 + tc * 4];
        float y0 = yt[tr * 2][m];
        float y1 = yt[tr * 2 + 1][m];
        acc[0][0] = fmaf(y0, wv.x, acc[0][0]); acc[0][1] = fmaf(y0, wv.y, acc[0][1]);
        acc[0][2] = fmaf(y0, wv.z, acc[0][2]); acc[0][3] = fmaf(y0, wv.w, acc[0][3]);
        acc[1][0] = fmaf(y1, wv.x, acc[1][0]); acc[1][1] = fmaf(y1, wv.y, acc[1][1]);
        acc[1][2] = fmaf(y1, wv.z, acc[1][2]); acc[1][3] = fmaf(y1, wv.w, acc[1][3]);
    }
    float4 sv = *(const float4*)&ss1[tc * 4];
    #pragma unroll
    for (int i = 0; i < 2; ++i) {
        int row = row0 + tr * 2 + i;
        float4 xv = *(const float4*)&x[row * 64 + tc * 4];
        float4 o;
        o.x = acc[i][0] + xv.x * sv.x;
        o.y = acc[i][1] + xv.y * sv.y;
        o.z = acc[i][2] + xv.z * sv.z;
        o.w = acc[i][3] + xv.w * sv.w;
        *(float4*)&h1[row * 64 + tc * 4] = o;
    }
}

// ---------------- K7: vdim2 (LN+mod) + MLP (64->96 gelu 96->64) + skip2 -> out
__global__ __launch_bounds__(256) void k7_vdim2_mlp(
    const float* __restrict__ h1, const float* __restrict__ mod2,
    const float* __restrict__ ln2_w, const float* __restrict__ ln2_b,
    const float* __restrict__ fc1_w, const float* __restrict__ fc1_b,
    const float* __restrict__ fc2_w, const float* __restrict__ fc2_b,
    const float* __restrict__ ss2, float* __restrict__ out) {
    __shared__ float x2t[32][66];
    __shared__ float tt[32][100];
    int t = threadIdx.x;
    int row0 = blockIdx.x * 32;
    int wave = t >> 6, lane = t & 63;
    int b = row0 >> 14;
    const float* m2 = mod2 + b * 128;

    for (int rr = 0; rr < 8; ++rr) {
        int rloc = wave * 8 + rr;
        float v = h1[(row0 + rloc) * 64 + lane];
        float s = v, s2 = v * v;
        #pragma unroll
        for (int off = 32; off; off >>= 1) { s += __shfl_xor(s, off); s2 += __shfl_xor(s2, off); }
        float mean = s * (1.0f / 64.0f);
        float var = s2 * (1.0f / 64.0f) - mean * mean;
        float inv = rsqrtf(var + 1e-6f);
        float xn = (v - mean) * inv * ln2_w[lane] + ln2_b[lane];
        x2t[rloc][lane] = xn * m2[lane] + m2[64 + lane];
    }
    __syncthreads();

    {
        int tr = t >> 4, tc = t & 15;
        float acc[2][6];
        #pragma unroll
        for (int i = 0; i < 2; ++i)
            #pragma unroll
            for (int j = 0; j < 6; ++j) acc[i][j] = 0.f;
        for (int c = 0; c < 64; ++c) {
            float x0 = x2t[tr * 2][c];
            float x1 = x2t[tr * 2 + 1][c];
            const float* wp = &fc1_w[c * 96 + tc * 6];
            float2 w01 = *(const float2*)wp;
            float2 w23 = *(const float2*)(wp + 2);
            float2 w45 = *(const float2*)(wp + 4);
            float w[6] = {w01.x, w01.y, w23.x, w23.y, w45.x, w45.y};
            #pragma unroll
            for (int j = 0; j < 6; ++j) {
                acc[0][j] = fmaf(x0, w[j], acc[0][j]);
                acc[1][j] = fmaf(x1, w[j], acc[1][j]);
            }
        }
        #pragma unroll
        for (int i = 0; i < 2; ++i) {
            #pragma unroll
            for (int j = 0; j < 6; ++j) {
                float a = acc[i][j] + fc1_b[tc * 6 + j];
                tt[tr * 2 + i][tc * 6 + j] = 0.5f * a * (1.f + erff(a * 0.70710678118654752f));
            }
        }
    }
    __syncthreads();

    {
        int tr = t >> 4, tc = t & 15;
        float acc[2][4];
        #pragma unroll
        for (int i = 0; i < 2; ++i)
            #pragma unroll
            for (int j = 0; j < 4; ++j) acc[i][j] = 0.f;
        for (int m = 0; m < 96; ++m) {
            float4 wv = *(const float4*)&fc2_w[m * 64 + tc * 4];
            float t0 = tt[tr * 2][m];
            float t1 = tt[tr * 2 + 1][m];
            acc[0][0] = fmaf(t0, wv.x, acc[0][0]); acc[0][1] = fmaf(t0, wv.y, acc[0][1]);
            acc[0][2] = fmaf(t0, wv.z, acc[0][2]); acc[0][3] = fmaf(t0, wv.w, acc[0][3]);
            acc[1][0] = fmaf(t1, wv.x, acc[1][0]); acc[1][1] = fmaf(t1, wv.y, acc[1][1]);
            acc[1][2] = fmaf(t1, wv.z, acc[1][2]); acc[1][3] = fmaf(t1, wv.w, acc[1][3]);
        }
        float4 sv = *(const float4*)&ss2[tc * 4];
        float4 bv = *(const float4*)&fc2_b[tc * 4];
        #pragma unroll
        for (int i = 0; i < 2; ++i) {
            int row = row0 + tr * 2 + i;
            float4 hv = *(const float4*)&h1[row * 64 + tc * 4];
            float4 o;
            o.x = hv.x * sv.x + acc[i][0] + bv.x;
            o.y = hv.y * sv.y + acc[i][1] + bv.y;
            o.z = hv.z * sv.z + acc[i][2] + bv.z;
            o.w = hv.w * sv.w + acc[i][3] + bv.w;
            *(float4*)&out[row * 64 + tc * 4] = o;
        }
    }
}

extern "C" void kernel_launch(void* const* d_in, const int* in_sizes, int n_in,
                              void* d_out, int out_size, void* d_ws, size_t ws_size,
                              hipStream_t stream) {
    const float* x        = (const float*)d_in[0];
    const float* cdp      = (const float*)d_in[1];
    const float* vd1      = (const float*)d_in[2];
    const float* ln1_w    = (const float*)d_in[3];
    const float* ln1_b    = (const float*)d_in[4];
    const float* ss1      = (const float*)d_in[5];
    const float* in_proj  = (const float*)d_in[6];
    const float* conv_w   = (const float*)d_in[7];
    const float* conv_b   = (const float*)d_in[8];
    const float* x_proj   = (const float*)d_in[9];
    const float* dt_w     = (const float*)d_in[10];
    const float* dt_b     = (const float*)d_in[11];
    const float* A_log    = (const float*)d_in[12];
    const float* Dp       = (const float*)d_in[13];
    const float* opw      = (const float*)d_in[14];
    const float* vd2      = (const float*)d_in[15];
    const float* ln2_w    = (const float*)d_in[16];
    const float* ln2_b    = (const float*)d_in[17];
    const float* ss2      = (const float*)d_in[18];
    const float* fc1_w    = (const float*)d_in[19];
    const float* fc1_b    = (const float*)d_in[20];
    const float* fc2_w    = (const float*)d_in[21];
    const float* fc2_b    = (const float*)d_in[22];

    float* ws = (float*)d_ws;
    const size_t NLD = (size_t)B_ * L_ * DI_;     // 3,145,728
    float* mod1  = ws;                            // 256
    float* mod2  = mod1 + 256;                    // 256
    float* Aneg  = mod2 + 256;                    // 1536
    float* Wcat  = Aneg + 2048;                   // 96*128 = 12288
    float* xsr   = ws + 16384;                    // NLD (pre-conv xs; reused as yb)
    float* zsb   = xsr + NLD;                     // NLD (silu(z); reused as h1)
    float* xsc   = zsb + NLD;                     // NLD
    float* dtb   = xsc + NLD;                     // NLD
    float* Bmb   = dtb + NLD;                     // 524288
    float* Cmb   = Bmb + (size_t)B_ * L_ * DS_;   // 524288
    float* aggf  = Cmb + (size_t)B_ * L_ * DS_;   // 2*NCT*NPAIR = 3,145,728
    float* initb = aggf + 2 * (size_t)NCT_ * NPAIR; // NCT*NPAIR = 1,572,864
    // total ~18.5M floats ~74 MB
    float* yb = xsr;   // xsr dead after k2
    float* h1 = zsb;   // zsb dead after s3_replay

    k0_prep<<<1, 256, 0, stream>>>(cdp, vd1, vd2, A_log, x_proj, dt_w, mod1, mod2, Aneg, Wcat);
    k1_vdim1_inproj<<<NROWS / 32, 256, 0, stream>>>(x, mod1, ln1_w, ln1_b, in_proj, xsr, zsb);
    k2_conv_gemm<<<NROWS / 32, 256, 0, stream>>>(xsr, conv_w, conv_b, Wcat, dt_b,
                                                 xsc, dtb, Bmb, Cmb);
    s1_agg<<<NCT_, 384, 0, stream>>>(dtb, xsc, Bmb, Aneg, (float2*)aggf);
    s2_scan<<<B_ * NPAIR, 512, 0, stream>>>((const float2*)aggf, initb);
    s3_replay<<<NCT_, 384, 0, stream>>>(dtb, xsc, Bmb, Cmb, Aneg, initb, Dp, zsb, yb);
    k6_outproj<<<NROWS / 32, 256, 0, stream>>>(yb, opw, x, ss1, h1);
    k7_vdim2_mlp<<<NROWS / 32, 256, 0, stream>>>(h1, mod2, ln2_w, ln2_b, fc1_w, fc1_b,
                                                 fc2_w, fc2_b, ss2, (float*)d_out);
}